// Round 4
// baseline (58.120 us; speedup 1.0000x reference)
//
#include <hip/hip_runtime.h>
#include <math.h>

#define W48 48
#define HD 2304
#define WHD 110592
#define NR 32
#define NB 8
#define QPP 27648            // float4 groups per (b,r) plane
#define CHUNKS 108           // QPP / 256
#define MAIN_BLOCKS 864      // NB * CHUNKS
#define NTOT 28311552.0

struct PPart { float s0, sx, sy; unsigned key; unsigned idx; }; // 20 B

// ---------------- fused single-pass kernel, LDS-deferred per-r reductions ----------------
__global__ __launch_bounds__(256)
void k_main(const float* __restrict__ feat, PPart* __restrict__ pp,
            double* __restrict__ blk) {
  __shared__ float    lds_s0[16 * 256];    // 16 KB  [r16][t]
  __shared__ unsigned lds_key[16 * 256];   // 16 KB  [r16][t]
  __shared__ unsigned lds_mc[256];         // 1 KB   packed mc, 2b per r16
  __shared__ float comb_s0[256], comb_sx[256], comb_sy[256];   // [eg][er]
  __shared__ unsigned comb_key[256], comb_idx[256];
  __shared__ double ld[4][5];

  const int bid = blockIdx.x;
  const int t = threadIdx.x;
  const int b = bid / CHUNKS;
  const int chunk = bid - b * CHUNKS;
  const int qbase = chunk * 256 + t;
  const float4* gptr = reinterpret_cast<const float4*>(feat) + (size_t)b * (NR * QPP) + qbase;

  const int p0 = qbase * 4;
  const float fi = (float)(p0 / HD);
  const float fj = (float)((p0 / W48) % W48);   // i,j constant over the 4 elems (4 | 48)
  const float rrq = fi * fi + fj * fj;

  float v1[4], v2[4], cp[4];
#pragma unroll
  for (int c = 0; c < 4; ++c) { v1[c] = -INFINITY; v2[c] = -INFINITY; cp[c] = 0.f; }
  float ssum = 0.f, sii = 0.f;
  unsigned mcpack = 0u;

  float4 nb0 = gptr[0];
  float4 nb1 = gptr[QPP];

#pragma unroll
  for (int r = 0; r < NR; ++r) {
    float4 v = nb0; nb0 = nb1;
    if (r < NR - 2) nb1 = gptr[(size_t)(r + 2) * QPP];

    float vv[4] = {v.x, v.y, v.z, v.w};
    float f2[4];
#pragma unroll
    for (int c = 0; c < 4; ++c) {
      float f = vv[c];
      f2[c] = f * f;
      cp[c] += f2[c];
      ssum += f;
      float nv2 = fmaxf(f, v2[c]);
      v2[c] = (f > v1[c]) ? v1[c] : nv2;     // top-2 insert, first-index semantics
      v1[c] = fmaxf(v1[c], f);
    }
    float s0t = (f2[0] + f2[1]) + (f2[2] + f2[3]);
    sii += s0t * rrq;

    float mv = vv[0]; int mc = 0;
#pragma unroll
    for (int c = 1; c < 4; ++c) { if (vv[c] > mv) { mv = vv[c]; mc = c; } }  // strict >
    unsigned u = __float_as_uint(mv);
    unsigned key = u ^ ((unsigned)((int)u >> 31) | 0x80000000u);  // order-preserving

    const int r16 = r & 15;
    mcpack |= (unsigned)mc << (2 * r16);
    lds_s0[r16 * 256 + t] = s0t;
    lds_key[r16 * 256 + t] = key;

    if (r16 == 15) {
      lds_mc[t] = mcpack; mcpack = 0u;
      __syncthreads();                      // S1: main-arena writes visible
      const int half = r >> 4;
      const int er = t & 15;                // which r16 this thread reduces
      const int eg = t >> 4;                // row-group (16 rows each)
      float es0 = 0.f, esx = 0.f, esy = 0.f;
      unsigned bk = 0u; int brow = 0;       // real keys are always > 0
#pragma unroll
      for (int k = 0; k < 16; ++k) {
        int row = eg * 16 + ((k + er) & 15);   // rotation: bank-decorrelated
        float s0v   = lds_s0[er * 256 + row];
        unsigned kv = lds_key[er * 256 + row];
        unsigned q = (unsigned)(chunk * 256 + row);
        float fiq = (float)(q / 576u);
        float fjq = (float)((q / 12u) % 48u);
        es0 += s0v;
        esx = fmaf(s0v, fiq, esx);
        esy = fmaf(s0v, fjq, esy);
        if (kv > bk || (kv == bk && row < brow)) { bk = kv; brow = row; }
      }
      unsigned wmc = (lds_mc[brow] >> (2 * er)) & 3u;
      unsigned bidx = (unsigned)((chunk * 256 + brow) * 4) + wmc;
      __syncthreads();                      // S2: main-arena reads done (safe to reuse)
      comb_s0[t] = es0; comb_sx[t] = esx; comb_sy[t] = esy;
      comb_key[t] = bk; comb_idx[t] = bidx;
      __syncthreads();                      // S3: comb visible
      if (t < 16) {
        float ps0 = 0.f, psx = 0.f, psy = 0.f;
        unsigned fk = 0u, fidx = 0xffffffffu;
#pragma unroll
        for (int g2 = 0; g2 < 16; ++g2) {
          int ii = g2 * 16 + t;
          ps0 += comb_s0[ii]; psx += comb_sx[ii]; psy += comb_sy[ii];
          unsigned ck = comb_key[ii], ci = comb_idx[ii];
          if (ck > fk || (ck == fk && ci < fidx)) { fk = ck; fidx = ci; }
        }
        int plane = b * NR + half * 16 + t;
        PPart o; o.s0 = ps0; o.sx = psx; o.sy = psy; o.key = fk; o.idx = fidx;
        pp[(size_t)plane * CHUNKS + chunk] = o;
      }
    }
  }

  // ---- div epilogue (f2@argmax == v1^2) + global sums ----
  float A = 0.f, Bs = 0.f, C = 0.f;
#pragma unroll
  for (int c = 0; c < 4; ++c) {
    float m1 = v1[c], m1sq = m1 * m1;
    float rest = cp[c] - m1sq;
    A  += m1sq * rest + v2[c] * v2[c] * m1sq;
    Bs += m1 * rest + v2[c] * m1sq;
    C  += cp[c];
  }
  double dA = A, dB = Bs, dC = C, dS = ssum, dI = sii;
  const int wave = t >> 6, lane = t & 63;
#pragma unroll
  for (int off = 32; off; off >>= 1) {
    dA += __shfl_down(dA, off);
    dB += __shfl_down(dB, off);
    dC += __shfl_down(dC, off);
    dS += __shfl_down(dS, off);
    dI += __shfl_down(dI, off);
  }
  if (lane == 0) { ld[wave][0]=dA; ld[wave][1]=dB; ld[wave][2]=dC; ld[wave][3]=dS; ld[wave][4]=dI; }
  __syncthreads();
  if (t == 0) {
    double a=0, bb=0, cc=0, ss=0, si=0;
#pragma unroll
    for (int w = 0; w < 4; ++w) { a+=ld[w][0]; bb+=ld[w][1]; cc+=ld[w][2]; ss+=ld[w][3]; si+=ld[w][4]; }
    blk[(size_t)bid*5+0]=a; blk[(size_t)bid*5+1]=bb; blk[(size_t)bid*5+2]=cc;
    blk[(size_t)bid*5+3]=ss; blk[(size_t)bid*5+4]=si;
  }
}

// ------------- stage 2: combine 108 chunk-partials per plane -------------
__global__ __launch_bounds__(128)
void k_planes(const PPart* __restrict__ pp, double* __restrict__ planeDis) {
  const int p = blockIdx.x;
  const int t = threadIdx.x;
  double s0 = 0, sx = 0, sy = 0;
  unsigned fkey = 0, idx = 0xffffffffu;
  if (t < CHUNKS) {
    PPart v = pp[(size_t)p * CHUNKS + t];
    s0 = v.s0; sx = v.sx; sy = v.sy; fkey = v.key; idx = v.idx;
  }
#pragma unroll
  for (int off = 32; off; off >>= 1) {
    s0 += __shfl_down(s0, off);
    sx += __shfl_down(sx, off);
    sy += __shfl_down(sy, off);
    unsigned ok = __shfl_down(fkey, off);
    unsigned oi = __shfl_down(idx, off);
    if (ok > fkey || (ok == fkey && oi < idx)) { fkey = ok; idx = oi; }
  }
  __shared__ double ls[2][3];
  __shared__ unsigned lk[2][2];
  const int wave = t >> 6, lane = t & 63;
  if (lane == 0) { ls[wave][0]=s0; ls[wave][1]=sx; ls[wave][2]=sy; lk[wave][0]=fkey; lk[wave][1]=idx; }
  __syncthreads();
  if (t == 0) {
    double a0=0, a1=0, a2=0; unsigned bk=0, bi=0xffffffffu;
#pragma unroll
    for (int w = 0; w < 2; ++w) {
      a0 += ls[w][0]; a1 += ls[w][1]; a2 += ls[w][2];
      if (lk[w][0] > bk || (lk[w][0]==bk && lk[w][1] < bi)) { bk = lk[w][0]; bi = lk[w][1]; }
    }
    int am = (int)bi;
    int mx = am / HD;
    int rem = am - mx * HD;
    int my = rem / W48;
    int mz = rem - my * W48;
    double dmx = mx, dmy = my, dmz = mz;
    // sum_k (mz-k)^2, k=0..47 = 48 mz^2 - 2256 mz + 35720 ; times W*H=2304
    planeDis[p] = (dmx*dmx + dmy*dmy) * a0 - 2.0*dmx*a1 - 2.0*dmy*a2
                + 2304.0 * (48.0*dmz*dmz - 2256.0*dmz + 35720.0);
  }
}

// ------------- stage 3: final scalars -------------
__global__ __launch_bounds__(256)
void k_fin(const double* __restrict__ planeDis, const double* __restrict__ blk,
           float* __restrict__ out) {
  const int t = threadIdx.x;
  double dis = planeDis[t];     // exactly 256 planes
  double A = 0, B = 0, C = 0, S = 0, SII = 0;
  for (int i = t; i < MAIN_BLOCKS; i += 256) {
    A   += blk[(size_t)i*5+0];
    B   += blk[(size_t)i*5+1];
    C   += blk[(size_t)i*5+2];
    S   += blk[(size_t)i*5+3];
    SII += blk[(size_t)i*5+4];
  }
#pragma unroll
  for (int off = 32; off; off >>= 1) {
    dis += __shfl_down(dis, off);
    A   += __shfl_down(A, off);
    B   += __shfl_down(B, off);
    C   += __shfl_down(C, off);
    S   += __shfl_down(S, off);
    SII += __shfl_down(SII, off);
  }
  __shared__ double ls[4][6];
  const int wave = t >> 6, lane = t & 63;
  if (lane == 0) {
    ls[wave][0]=dis; ls[wave][1]=A; ls[wave][2]=B; ls[wave][3]=C; ls[wave][4]=S; ls[wave][5]=SII;
  }
  __syncthreads();
  if (t == 0) {
    double td=0, tA=0, tB=0, tC=0, tS=0, tI=0;
#pragma unroll
    for (int w = 0; w < 4; ++w) {
      td+=ls[w][0]; tA+=ls[w][1]; tB+=ls[w][2]; tC+=ls[w][3]; tS+=ls[w][4]; tI+=ls[w][5];
    }
    double mgr = tS / NTOT;
    out[0] = (float)((td + tI) / NTOT);
    out[1] = (float)((tA - 2.0*mgr*tB + mgr*mgr*tC) / NTOT);
  }
}

extern "C" void kernel_launch(void* const* d_in, const int* in_sizes, int n_in,
                              void* d_out, int out_size, void* d_ws, size_t ws_size,
                              hipStream_t stream) {
  // inputs: [0]=backbone_feature (unused), [1]=grouping_result (unused), [2]=feature
  const float* feat = (const float*)d_in[2];
  float* out = (float*)d_out;

  PPart* pp = (PPart*)d_ws;                                   // 256*108*20 = 552960 B
  double* blk = (double*)((char*)d_ws + 552960);              // 864*5*8 = 34560 B
  double* planeDis = (double*)((char*)d_ws + 552960 + 34560); // 256*8 = 2048 B

  k_main<<<MAIN_BLOCKS, 256, 0, stream>>>(feat, pp, blk);
  k_planes<<<256, 128, 0, stream>>>(pp, planeDis);
  k_fin<<<1, 256, 0, stream>>>(planeDis, blk, out);
}

// Round 5
// 39.147 us; speedup vs baseline: 1.4847x; 1.4847x over previous
//
#include <hip/hip_runtime.h>
#include <math.h>

#define W48 48
#define HD 2304
#define WHD 110592
#define NR 32
#define NB 8
#define QPP 27648            // float4 groups per (b,r) plane
#define CHUNKS 108           // QPP / 256
#define MAIN_BLOCKS 864      // NB * CHUNKS
#define NTOT 28311552.0

struct PPart { float s0, sx, sy; unsigned key; unsigned idx; }; // 20 B

// ---------------- fused single-pass kernel, LDS-deferred per-r reductions ----------------
__global__ __launch_bounds__(256, 4)   // cap VGPR at 128 -> 4 waves/SIMD
void k_main(const float* __restrict__ feat, PPart* __restrict__ pp,
            double* __restrict__ blk) {
  __shared__ float    lds_s0[16 * 256];    // 16 KB  [r16][t]
  __shared__ unsigned lds_key[16 * 256];   // 16 KB  [r16][t]
  __shared__ unsigned lds_mc[256];         // 1 KB   packed mc, 2b per r16
  __shared__ float comb_s0[256], comb_sx[256], comb_sy[256];   // [eg][er]
  __shared__ unsigned comb_key[256], comb_idx[256];
  __shared__ double ld[4][5];

  const int bid = blockIdx.x;
  const int t = threadIdx.x;
  const int b = bid / CHUNKS;
  const int chunk = bid - b * CHUNKS;
  const int qbase = chunk * 256 + t;
  const float4* gptr = reinterpret_cast<const float4*>(feat) + (size_t)b * (NR * QPP) + qbase;

  const int p0 = qbase * 4;
  const float fi = (float)(p0 / HD);
  const float fj = (float)((p0 / W48) % W48);   // i,j constant over the 4 elems (4 | 48)
  const float rrq = fi * fi + fj * fj;

  float v1[4], v2[4], cp[4];
#pragma unroll
  for (int c = 0; c < 4; ++c) { v1[c] = -INFINITY; v2[c] = -INFINITY; cp[c] = 0.f; }
  float ssum = 0.f, sii = 0.f;
  unsigned mcpack = 0u;

  float4 nb0 = gptr[0];
  float4 nb1 = gptr[QPP];
  float4 nb2 = gptr[2 * (size_t)QPP];

  for (int half = 0; half < 2; ++half) {
#pragma unroll 4
    for (int rr = 0; rr < 16; ++rr) {
      const int r = half * 16 + rr;
      float4 v = nb0; nb0 = nb1; nb1 = nb2;
      if (r < NR - 3) nb2 = gptr[(size_t)(r + 3) * QPP];

      float vv[4] = {v.x, v.y, v.z, v.w};
      float f2[4];
#pragma unroll
      for (int c = 0; c < 4; ++c) {
        float f = vv[c];
        f2[c] = f * f;
        cp[c] += f2[c];
        ssum += f;
        float nv2 = fmaxf(f, v2[c]);
        v2[c] = (f > v1[c]) ? v1[c] : nv2;     // top-2 insert, first-index semantics
        v1[c] = fmaxf(v1[c], f);
      }
      float s0t = (f2[0] + f2[1]) + (f2[2] + f2[3]);
      sii += s0t * rrq;

      float mv = vv[0]; int mc = 0;
#pragma unroll
      for (int c = 1; c < 4; ++c) { if (vv[c] > mv) { mv = vv[c]; mc = c; } }  // strict >
      unsigned u = __float_as_uint(mv);
      unsigned key = u ^ ((unsigned)((int)u >> 31) | 0x80000000u);  // order-preserving

      mcpack |= (unsigned)mc << (2 * rr);
      lds_s0[rr * 256 + t] = s0t;
      lds_key[rr * 256 + t] = key;
    }

    // ---- epilogue for this half: transpose-reduce 16 r's in parallel ----
    lds_mc[t] = mcpack; mcpack = 0u;
    __syncthreads();                      // S1: main-arena writes visible
    const int er = t & 15;                // which r this thread reduces
    const int eg = t >> 4;                // row-group (16 rows each)
    float es0 = 0.f, esx = 0.f, esy = 0.f;
    unsigned bk = 0u; int brow = 0;       // real keys are always > 0
#pragma unroll
    for (int k = 0; k < 16; ++k) {
      int row = eg * 16 + ((k + er) & 15);   // rotation: bank-decorrelated
      float s0v   = lds_s0[er * 256 + row];
      unsigned kv = lds_key[er * 256 + row];
      unsigned q = (unsigned)(chunk * 256 + row);
      float fiq = (float)(q / 576u);
      float fjq = (float)((q / 12u) % 48u);
      es0 += s0v;
      esx = fmaf(s0v, fiq, esx);
      esy = fmaf(s0v, fjq, esy);
      if (kv > bk || (kv == bk && row < brow)) { bk = kv; brow = row; }
    }
    unsigned wmc = (lds_mc[brow] >> (2 * er)) & 3u;
    unsigned bidx = (unsigned)((chunk * 256 + brow) * 4) + wmc;
    __syncthreads();                      // S2: main-arena reads done (safe to reuse)
    comb_s0[t] = es0; comb_sx[t] = esx; comb_sy[t] = esy;
    comb_key[t] = bk; comb_idx[t] = bidx;
    __syncthreads();                      // S3: comb visible
    if (t < 16) {
      float ps0 = 0.f, psx = 0.f, psy = 0.f;
      unsigned fk = 0u, fidx = 0xffffffffu;
#pragma unroll
      for (int g2 = 0; g2 < 16; ++g2) {
        int ii = g2 * 16 + t;
        ps0 += comb_s0[ii]; psx += comb_sx[ii]; psy += comb_sy[ii];
        unsigned ck = comb_key[ii], ci = comb_idx[ii];
        if (ck > fk || (ck == fk && ci < fidx)) { fk = ck; fidx = ci; }
      }
      int plane = b * NR + half * 16 + t;
      PPart o; o.s0 = ps0; o.sx = psx; o.sy = psy; o.key = fk; o.idx = fidx;
      pp[(size_t)plane * CHUNKS + chunk] = o;
    }
  }

  // ---- div epilogue (f2@argmax == v1^2) + global sums ----
  float A = 0.f, Bs = 0.f, C = 0.f;
#pragma unroll
  for (int c = 0; c < 4; ++c) {
    float m1 = v1[c], m1sq = m1 * m1;
    float rest = cp[c] - m1sq;
    A  += m1sq * rest + v2[c] * v2[c] * m1sq;
    Bs += m1 * rest + v2[c] * m1sq;
    C  += cp[c];
  }
  double dA = A, dB = Bs, dC = C, dS = ssum, dI = sii;
  const int wave = t >> 6, lane = t & 63;
#pragma unroll
  for (int off = 32; off; off >>= 1) {
    dA += __shfl_down(dA, off);
    dB += __shfl_down(dB, off);
    dC += __shfl_down(dC, off);
    dS += __shfl_down(dS, off);
    dI += __shfl_down(dI, off);
  }
  if (lane == 0) { ld[wave][0]=dA; ld[wave][1]=dB; ld[wave][2]=dC; ld[wave][3]=dS; ld[wave][4]=dI; }
  __syncthreads();
  if (t == 0) {
    double a=0, bb=0, cc=0, ss=0, si=0;
#pragma unroll
    for (int w = 0; w < 4; ++w) { a+=ld[w][0]; bb+=ld[w][1]; cc+=ld[w][2]; ss+=ld[w][3]; si+=ld[w][4]; }
    blk[(size_t)bid*5+0]=a; blk[(size_t)bid*5+1]=bb; blk[(size_t)bid*5+2]=cc;
    blk[(size_t)bid*5+3]=ss; blk[(size_t)bid*5+4]=si;
  }
}

// ------------- stage 2: combine 108 chunk-partials per plane -------------
__global__ __launch_bounds__(128)
void k_planes(const PPart* __restrict__ pp, double* __restrict__ planeDis) {
  const int p = blockIdx.x;
  const int t = threadIdx.x;
  double s0 = 0, sx = 0, sy = 0;
  unsigned fkey = 0, idx = 0xffffffffu;
  if (t < CHUNKS) {
    PPart v = pp[(size_t)p * CHUNKS + t];
    s0 = v.s0; sx = v.sx; sy = v.sy; fkey = v.key; idx = v.idx;
  }
#pragma unroll
  for (int off = 32; off; off >>= 1) {
    s0 += __shfl_down(s0, off);
    sx += __shfl_down(sx, off);
    sy += __shfl_down(sy, off);
    unsigned ok = __shfl_down(fkey, off);
    unsigned oi = __shfl_down(idx, off);
    if (ok > fkey || (ok == fkey && oi < idx)) { fkey = ok; idx = oi; }
  }
  __shared__ double ls[2][3];
  __shared__ unsigned lk[2][2];
  const int wave = t >> 6, lane = t & 63;
  if (lane == 0) { ls[wave][0]=s0; ls[wave][1]=sx; ls[wave][2]=sy; lk[wave][0]=fkey; lk[wave][1]=idx; }
  __syncthreads();
  if (t == 0) {
    double a0=0, a1=0, a2=0; unsigned bk=0, bi=0xffffffffu;
#pragma unroll
    for (int w = 0; w < 2; ++w) {
      a0 += ls[w][0]; a1 += ls[w][1]; a2 += ls[w][2];
      if (lk[w][0] > bk || (lk[w][0]==bk && lk[w][1] < bi)) { bk = lk[w][0]; bi = lk[w][1]; }
    }
    int am = (int)bi;
    int mx = am / HD;
    int rem = am - mx * HD;
    int my = rem / W48;
    int mz = rem - my * W48;
    double dmx = mx, dmy = my, dmz = mz;
    // sum_k (mz-k)^2, k=0..47 = 48 mz^2 - 2256 mz + 35720 ; times W*H=2304
    planeDis[p] = (dmx*dmx + dmy*dmy) * a0 - 2.0*dmx*a1 - 2.0*dmy*a2
                + 2304.0 * (48.0*dmz*dmz - 2256.0*dmz + 35720.0);
  }
}

// ------------- stage 3: final scalars -------------
__global__ __launch_bounds__(256)
void k_fin(const double* __restrict__ planeDis, const double* __restrict__ blk,
           float* __restrict__ out) {
  const int t = threadIdx.x;
  double dis = planeDis[t];     // exactly 256 planes
  double A = 0, B = 0, C = 0, S = 0, SII = 0;
  for (int i = t; i < MAIN_BLOCKS; i += 256) {
    A   += blk[(size_t)i*5+0];
    B   += blk[(size_t)i*5+1];
    C   += blk[(size_t)i*5+2];
    S   += blk[(size_t)i*5+3];
    SII += blk[(size_t)i*5+4];
  }
#pragma unroll
  for (int off = 32; off; off >>= 1) {
    dis += __shfl_down(dis, off);
    A   += __shfl_down(A, off);
    B   += __shfl_down(B, off);
    C   += __shfl_down(C, off);
    S   += __shfl_down(S, off);
    SII += __shfl_down(SII, off);
  }
  __shared__ double ls[4][6];
  const int wave = t >> 6, lane = t & 63;
  if (lane == 0) {
    ls[wave][0]=dis; ls[wave][1]=A; ls[wave][2]=B; ls[wave][3]=C; ls[wave][4]=S; ls[wave][5]=SII;
  }
  __syncthreads();
  if (t == 0) {
    double td=0, tA=0, tB=0, tC=0, tS=0, tI=0;
#pragma unroll
    for (int w = 0; w < 4; ++w) {
      td+=ls[w][0]; tA+=ls[w][1]; tB+=ls[w][2]; tC+=ls[w][3]; tS+=ls[w][4]; tI+=ls[w][5];
    }
    double mgr = tS / NTOT;
    out[0] = (float)((td + tI) / NTOT);
    out[1] = (float)((tA - 2.0*mgr*tB + mgr*mgr*tC) / NTOT);
  }
}

extern "C" void kernel_launch(void* const* d_in, const int* in_sizes, int n_in,
                              void* d_out, int out_size, void* d_ws, size_t ws_size,
                              hipStream_t stream) {
  // inputs: [0]=backbone_feature (unused), [1]=grouping_result (unused), [2]=feature
  const float* feat = (const float*)d_in[2];
  float* out = (float*)d_out;

  PPart* pp = (PPart*)d_ws;                                   // 256*108*20 = 552960 B
  double* blk = (double*)((char*)d_ws + 552960);              // 864*5*8 = 34560 B
  double* planeDis = (double*)((char*)d_ws + 552960 + 34560); // 256*8 = 2048 B

  k_main<<<MAIN_BLOCKS, 256, 0, stream>>>(feat, pp, blk);
  k_planes<<<256, 128, 0, stream>>>(pp, planeDis);
  k_fin<<<1, 256, 0, stream>>>(planeDis, blk, out);
}